// Round 11
// baseline (635.301 us; speedup 1.0000x reference)
//
#include <hip/hip_runtime.h>
#include <hip/hip_bf16.h>

typedef unsigned short u16;

#define NN    100000     // total nodes
#define NU    50000      // users
#define DD    64         // latdim
#define HHY   128        // hyperNum
#define EE    1600000    // nnz
#define NCHK  384        // split-K chunks for lat (part = 12.58 MB, fits slab2 upper half)
#define CROWS 261        // ceil(NN/NCHK)
#define NSB   391        // ceil(NN/256) scan blocks
#define SCB   6250       // scatter / prep chunk count (EE/256)
#define LPB   768        // latpart flat blocks (NCHK chunks x 2 h-halves)

__device__ __forceinline__ float us2f(u16 u) {
    union { unsigned int i; float f; } v; v.i = ((unsigned int)u) << 16; return v.f;
}
__device__ __forceinline__ u16 f2us(float f) {
    __hip_bfloat16 b = __float2bfloat16(f);
    return *reinterpret_cast<u16*>(&b);
}
__device__ __forceinline__ float lrelu(float x) { return x > 0.f ? x : 0.5f * x; }

// ================= device bodies (shared by fused wrappers) =================

// allhyper for 16 rows/block, Hyper staged in LDS, 2 rows per thread.
__device__ __forceinline__ void allhyper_body(int ab, float* hlds,
        const float4* __restrict__ u, const float4* __restrict__ it,
        const float* __restrict__ Hyper, u16* __restrict__ hyp) {
    int t = threadIdx.x;
    // stage Hyper[64][128] fp32 (2048 float4) into LDS, coalesced
    const float4* hsrc = (const float4*)Hyper;
    float4* hdst = (float4*)hlds;
#pragma unroll
    for (int i = 0; i < 8; i++) hdst[i * 256 + t] = hsrc[i * 256 + t];
    __syncthreads();
    int hg = t & 31;                       // 32 groups of 4 h
    int rs = t >> 5;                       // 8 row-pair slots
    int n0 = ab * 16 + rs * 2;             // rows n0, n0+1
    int n1 = n0 + 1;
    const float4* s0 = (n0 < NU) ? (u + (size_t)n0 * 16) : (it + (size_t)(n0 - NU) * 16);
    const float4* s1 = (n1 < NU) ? (u + (size_t)n1 * 16) : (it + (size_t)(n1 - NU) * 16);
    float a00 = 0.f, a01 = 0.f, a02 = 0.f, a03 = 0.f;
    float a10 = 0.f, a11 = 0.f, a12 = 0.f, a13 = 0.f;
#pragma unroll
    for (int half = 0; half < 2; half++) {
        float4 e0[8], e1[8];
#pragma unroll
        for (int i = 0; i < 8; i++) { e0[i] = s0[half * 8 + i]; e1[i] = s1[half * 8 + i]; }
#pragma unroll
        for (int i = 0; i < 8; i++) {
            float ev0[4] = { e0[i].x, e0[i].y, e0[i].z, e0[i].w };
            float ev1[4] = { e1[i].x, e1[i].y, e1[i].z, e1[i].w };
#pragma unroll
            for (int k = 0; k < 4; k++) {
                int d = half * 32 + i * 4 + k;
                float4 hq = *(const float4*)(hlds + d * HHY + hg * 4);
                a00 += ev0[k] * hq.x; a01 += ev0[k] * hq.y;
                a02 += ev0[k] * hq.z; a03 += ev0[k] * hq.w;
                a10 += ev1[k] * hq.x; a11 += ev1[k] * hq.y;
                a12 += ev1[k] * hq.z; a13 += ev1[k] * hq.w;
            }
        }
    }
    u16* o0 = hyp + (size_t)n0 * HHY + hg * 4;
    o0[0] = f2us(a00); o0[1] = f2us(a01); o0[2] = f2us(a02); o0[3] = f2us(a03);
    u16* o1 = hyp + (size_t)n1 * HHY + hg * 4;
    o1[0] = f2us(a10); o1[1] = f2us(a11); o1[2] = f2us(a12); o1[3] = f2us(a13);
}

// latpart: x4 n-unroll -> 20 independent loads in flight per thread (MLP)
__device__ __forceinline__ void latpart_body(int chunk, int yy,
        const u16* __restrict__ cur, const u16* __restrict__ hyp,
        float* __restrict__ part) {
    int t = threadIdx.x;
    int w = t >> 6, d = t & 63;
    int h0 = (yy * 4 + w) * 16;
    int c0 = chunk * CROWS;
    int c1 = c0 + CROWS; if (c1 > NN) c1 = NN;
    float acc[16];
#pragma unroll
    for (int j = 0; j < 16; j++) acc[j] = 0.f;
    int n = c0;
    for (; n + 4 <= c1; n += 4) {
        const u16* cp = cur + (size_t)n * DD + d;
        u16 ca = cp[0], cb = cp[DD], cc = cp[2 * DD], cd = cp[3 * DD];
        const ushort4* ha4 = (const ushort4*)(hyp + (size_t)n * HHY + h0);
        const ushort4* hb4 = (const ushort4*)(hyp + (size_t)(n + 1) * HHY + h0);
        const ushort4* hc4 = (const ushort4*)(hyp + (size_t)(n + 2) * HHY + h0);
        const ushort4* hd4 = (const ushort4*)(hyp + (size_t)(n + 3) * HHY + h0);
        u16 ua[16], ub[16], uc[16], ud[16];
        *(ushort4*)(ua + 0) = ha4[0]; *(ushort4*)(ua + 4) = ha4[1];
        *(ushort4*)(ua + 8) = ha4[2]; *(ushort4*)(ua + 12) = ha4[3];
        *(ushort4*)(ub + 0) = hb4[0]; *(ushort4*)(ub + 4) = hb4[1];
        *(ushort4*)(ub + 8) = hb4[2]; *(ushort4*)(ub + 12) = hb4[3];
        *(ushort4*)(uc + 0) = hc4[0]; *(ushort4*)(uc + 4) = hc4[1];
        *(ushort4*)(uc + 8) = hc4[2]; *(ushort4*)(uc + 12) = hc4[3];
        *(ushort4*)(ud + 0) = hd4[0]; *(ushort4*)(ud + 4) = hd4[1];
        *(ushort4*)(ud + 8) = hd4[2]; *(ushort4*)(ud + 12) = hd4[3];
        float fa = us2f(ca), fb = us2f(cb), fc = us2f(cc), fd = us2f(cd);
#pragma unroll
        for (int j = 0; j < 16; j++)
            acc[j] += us2f(ua[j]) * fa + us2f(ub[j]) * fb
                    + us2f(uc[j]) * fc + us2f(ud[j]) * fd;
    }
    for (; n < c1; n++) {
        float cv = us2f(cur[(size_t)n * DD + d]);
        const ushort4* hp = (const ushort4*)(hyp + (size_t)n * HHY + h0);
        u16 ha[16];
        *(ushort4*)(ha + 0)  = hp[0];
        *(ushort4*)(ha + 4)  = hp[1];
        *(ushort4*)(ha + 8)  = hp[2];
        *(ushort4*)(ha + 12) = hp[3];
#pragma unroll
        for (int j = 0; j < 16; j++) acc[j] += us2f(ha[j]) * cv;
    }
#pragma unroll
    for (int j = 0; j < 16; j++)
        part[((size_t)chunk * HHY + h0 + j) * DD + d] = acc[j];
}

// single-pass scatter via precomputed positions (pos read is coalesced)
__device__ __forceinline__ void scatter_body(int chunk,
        const int* __restrict__ pos,
        const int* __restrict__ cols, const float* __restrict__ vals,
        int2* __restrict__ csr) {
    int e = chunk * 256 + threadIdx.x;     // < EE
    csr[pos[e]] = make_int2(cols[e], __float_as_int(vals[e]));
}

__device__ __forceinline__ void spmm_body(int b,
        const int* __restrict__ row_start, const int2* __restrict__ csr,
        const u16* __restrict__ gate, float* __restrict__ out0) {
    int w = threadIdx.x >> 6, d = threadIdx.x & 63;
    int row = b * 4 + w;                   // b < NN/4 -> row < NN
    int s = row_start[row], e = row_start[row + 1];
    float a0 = 0.f, a1 = 0.f, a2 = 0.f, a3 = 0.f;
    float a4 = 0.f, a5 = 0.f, a6 = 0.f, a7 = 0.f;
    int j = s;
    for (; j + 8 <= e; j += 8) {
        int2 c0 = csr[j],     c1 = csr[j + 1], c2 = csr[j + 2], c3 = csr[j + 3];
        int2 c4 = csr[j + 4], c5 = csr[j + 5], c6 = csr[j + 6], c7 = csr[j + 7];
        float g0 = us2f(gate[(size_t)c0.x * DD + d]);
        float g1 = us2f(gate[(size_t)c1.x * DD + d]);
        float g2 = us2f(gate[(size_t)c2.x * DD + d]);
        float g3 = us2f(gate[(size_t)c3.x * DD + d]);
        float g4 = us2f(gate[(size_t)c4.x * DD + d]);
        float g5 = us2f(gate[(size_t)c5.x * DD + d]);
        float g6 = us2f(gate[(size_t)c6.x * DD + d]);
        float g7 = us2f(gate[(size_t)c7.x * DD + d]);
        a0 += __int_as_float(c0.y) * g0;
        a1 += __int_as_float(c1.y) * g1;
        a2 += __int_as_float(c2.y) * g2;
        a3 += __int_as_float(c3.y) * g3;
        a4 += __int_as_float(c4.y) * g4;
        a5 += __int_as_float(c5.y) * g5;
        a6 += __int_as_float(c6.y) * g6;
        a7 += __int_as_float(c7.y) * g7;
    }
    for (; j + 4 <= e; j += 4) {
        int2 c0 = csr[j], c1 = csr[j + 1], c2 = csr[j + 2], c3 = csr[j + 3];
        float g0 = us2f(gate[(size_t)c0.x * DD + d]);
        float g1 = us2f(gate[(size_t)c1.x * DD + d]);
        float g2 = us2f(gate[(size_t)c2.x * DD + d]);
        float g3 = us2f(gate[(size_t)c3.x * DD + d]);
        a0 += __int_as_float(c0.y) * g0;
        a1 += __int_as_float(c1.y) * g1;
        a2 += __int_as_float(c2.y) * g2;
        a3 += __int_as_float(c3.y) * g3;
    }
    for (; j < e; j++) {
        int2 cv = csr[j];
        a0 += __int_as_float(cv.y) * us2f(gate[(size_t)cv.x * DD + d]);
    }
    float acc = ((a0 + a1) + (a2 + a3)) + ((a4 + a5) + (a6 + a7));
    out0[(size_t)row * DD + d] = lrelu(acc);
}

__device__ __forceinline__ void latreduce_body(int lb,
        const float* __restrict__ part, float* __restrict__ lat) {
    int idx = lb * 256 + threadIdx.x;      // h*64+d, 8192 total
    float s0 = 0.f, s1 = 0.f, s2 = 0.f, s3 = 0.f;
    for (int c = 0; c < NCHK; c += 4) {
        s0 += part[(size_t)(c + 0) * HHY * DD + idx];
        s1 += part[(size_t)(c + 1) * HHY * DD + idx];
        s2 += part[(size_t)(c + 2) * HHY * DD + idx];
        s3 += part[(size_t)(c + 3) * HHY * DD + idx];
    }
    lat[idx] = lrelu((s0 + s1) + (s2 + s3));
}

// ================= kernels =================

// fused: prep (embeds0 -> bf16 cur AND gate0) + hist || allhyper (LDS-staged)
__global__ __launch_bounds__(256) void k_hp_ah(const int* __restrict__ rows,
                                               int* __restrict__ cnt,
                                               int* __restrict__ ranks,
                                               const float4* __restrict__ u,
                                               const float4* __restrict__ it,
                                               ushort4* __restrict__ cur,
                                               const float* __restrict__ Hyper,
                                               u16* __restrict__ hyp,
                                               const float4* __restrict__ z,
                                               ushort4* __restrict__ gate0) {
    __shared__ float hlds[DD * HHY];       // 32 KB (allhyper branch only)
    int bid = blockIdx.x;
    int p = bid & 1, q = bid >> 1;
    if (p == 0) {
        int e = q * 256 + threadIdx.x;     // < EE
        const int HALF = NU * DD / 4;      // 800000
        float4 f = (e < HALF) ? u[e] : it[e - HALF];
        ushort4 c; c.x = f2us(f.x); c.y = f2us(f.y); c.z = f2us(f.z); c.w = f2us(f.w);
        cur[e] = c;
        // gate0 = bf16( bf16(embeds0) * (2*sigmoid(z)-1) ), identical to old k_gate
        float4 zz = z[e];
        ushort4 g;
        g.x = f2us(us2f(c.x) * (2.f / (1.f + __expf(-zz.x)) - 1.f));
        g.y = f2us(us2f(c.y) * (2.f / (1.f + __expf(-zz.y)) - 1.f));
        g.z = f2us(us2f(c.z) * (2.f / (1.f + __expf(-zz.z)) - 1.f));
        g.w = f2us(us2f(c.w) * (2.f / (1.f + __expf(-zz.w)) - 1.f));
        gate0[e] = g;
        ranks[e] = atomicAdd(&cnt[rows[e]], 1);
    } else {
        allhyper_body(q, hlds, u, it, Hyper, hyp);
    }
}

// phase 1: per-block sums of cnt (256 counts per block)
__global__ __launch_bounds__(256) void k_blocksum(const int* __restrict__ cnt,
                                                  int* __restrict__ bsum) {
    __shared__ int s[256];
    int t = threadIdx.x;
    int i = blockIdx.x * 256 + t;
    s[t] = (i < NN) ? cnt[i] : 0;
    __syncthreads();
    for (int off = 128; off > 0; off >>= 1) {
        if (t < off) s[t] += s[t + off];
        __syncthreads();
    }
    if (t == 0) bsum[blockIdx.x] = s[0];
}

// phase 2: exclusive scan of the 391 block sums (single small block)
__global__ __launch_bounds__(512) void k_scanb(int* __restrict__ bsum) {
    __shared__ int s[512];
    int t = threadIdx.x;
    int v = (t < NSB) ? bsum[t] : 0;
    s[t] = v;
    __syncthreads();
    for (int off = 1; off < 512; off <<= 1) {
        int add = (t >= off) ? s[t - off] : 0;
        __syncthreads();
        s[t] += add;
        __syncthreads();
    }
    if (t < NSB) bsum[t] = s[t] - v;   // exclusive
}

// phase 3: block-local scan + block offset -> row_start
__global__ __launch_bounds__(256) void k_scanfinal(const int* __restrict__ cnt,
                                                   const int* __restrict__ bsum,
                                                   int* __restrict__ row_start) {
    __shared__ int s[256];
    int t = threadIdx.x;
    int i = blockIdx.x * 256 + t;
    int v = (i < NN) ? cnt[i] : 0;
    s[t] = v;
    __syncthreads();
    for (int off = 1; off < 256; off <<= 1) {
        int add = (t >= off) ? s[t - off] : 0;
        __syncthreads();
        s[t] += add;
        __syncthreads();
    }
    int excl = s[t] - v + bsum[blockIdx.x];
    if (i < NN) row_start[i] = excl;
    if (i == NN - 1) row_start[NN] = excl + v;   // total nnz
}

// pos[e] = final CSR position of edge e (coalesced; row_start gather is L2-resident)
__global__ __launch_bounds__(256) void k_pos(const int* __restrict__ rows,
                                             const int* __restrict__ ranks,
                                             const int* __restrict__ row_start,
                                             int* __restrict__ pos) {
    int e = blockIdx.x * 256 + threadIdx.x;   // grid = SCB -> e < EE
    pos[e] = row_start[rows[e]] + ranks[e];
}

// fused layer-0: latpart0 (first 768 long blocks) || single-pass scatter (6250)
__global__ __launch_bounds__(256) void k_fused0(const int* __restrict__ pos,
                                                const int* __restrict__ cols,
                                                const float* __restrict__ vals,
                                                int2* __restrict__ csr,
                                                const u16* __restrict__ cur,
                                                const u16* __restrict__ hyp,
                                                float* __restrict__ part) {
    int bid = blockIdx.x;
    if (bid < LPB) latpart_body(bid >> 1, bid & 1, cur, hyp, part);
    else           scatter_body(bid - LPB, pos, cols, vals, csr);
}

// fused: latreduce (32 blocks, first) || spmm (25000 blocks)  [layer 0]
__global__ __launch_bounds__(256) void k_fused_sl(const int* __restrict__ row_start,
                                                  const int2* __restrict__ csr,
                                                  const u16* __restrict__ gate,
                                                  float* __restrict__ out0,
                                                  const float* __restrict__ part,
                                                  float* __restrict__ lat) {
    int bid = blockIdx.x;
    if (bid < 32) latreduce_body(bid, part, lat);
    else          spmm_body(bid - 32, row_start, csr, gate, out0);
}

// fused layer-1: latpart1 (768 first) || spmm1 (25000) — both ready after hyperlat(l0)
__global__ __launch_bounds__(256) void k_lsp1(const int* __restrict__ row_start,
                                              const int2* __restrict__ csr,
                                              const u16* __restrict__ gate,
                                              float* __restrict__ out0,
                                              const u16* __restrict__ cur,
                                              const u16* __restrict__ hyp,
                                              float* __restrict__ part) {
    int bid = blockIdx.x;
    if (bid < LPB) latpart_body(bid >> 1, bid & 1, cur, hyp, part);
    else           spmm_body(bid - LPB, row_start, csr, gate, out0);
}

// standalone latreduce (layer 1)
__global__ __launch_bounds__(256) void k_latred(const float* __restrict__ part,
                                                float* __restrict__ lat) {
    latreduce_body(blockIdx.x, part, lat);
}

// hyperLat = leaky(hyp @ lat); outL = hyperLat; cur = bf16(hyperLat + tem);
// if emit: gate = bf16(cur) * (2*sigmoid(z)-1)  (next layer's gate, fused epilogue)
__global__ __launch_bounds__(256) void k_hyperlat(const u16* __restrict__ hyp,
                                                  const float* __restrict__ lat,
                                                  const float* __restrict__ tem0,
                                                  float* __restrict__ outL,
                                                  u16* __restrict__ cur,
                                                  const float* __restrict__ z,
                                                  u16* __restrict__ gate,
                                                  int emit) {
    __shared__ float lds[HHY * DD];   // 32 KB
    int t = threadIdx.x;
    for (int i = t; i < HHY * DD; i += 256) lds[i] = lat[i];
    __syncthreads();
    int w = t >> 6, d = t & 63;
    int r0 = blockIdx.x * 16 + w * 4;
    float acc[4] = {0.f, 0.f, 0.f, 0.f};
    for (int h0 = 0; h0 < HHY; h0 += 8) {
        u16 hr[4][8];
#pragma unroll
        for (int r = 0; r < 4; r++) {
            const ushort4* pp = (const ushort4*)(hyp + (size_t)(r0 + r) * HHY + h0);
            ushort4 a = pp[0], b = pp[1];
            hr[r][0] = a.x; hr[r][1] = a.y; hr[r][2] = a.z; hr[r][3] = a.w;
            hr[r][4] = b.x; hr[r][5] = b.y; hr[r][6] = b.z; hr[r][7] = b.w;
        }
#pragma unroll
        for (int j = 0; j < 8; j++) {
            float lv = lds[(h0 + j) * DD + d];
#pragma unroll
            for (int r = 0; r < 4; r++) acc[r] += us2f(hr[r][j]) * lv;
        }
    }
#pragma unroll
    for (int r = 0; r < 4; r++) {
        size_t off = (size_t)(r0 + r) * DD + d;
        float hl = lrelu(acc[r]);
        float tem = tem0[off];
        u16 cb = f2us(hl + tem);
        outL[off] = hl;                 // fp32 output
        cur[off] = cb;                  // bf16 intermediate for next layer
        if (emit) {
            float zz = z[off];
            gate[off] = f2us(us2f(cb) * (2.f / (1.f + __expf(-zz)) - 1.f));
        }
    }
}

// ---------------- launch ----------------

extern "C" void kernel_launch(void* const* d_in, const int* in_sizes, int n_in,
                              void* d_out, int out_size, void* d_ws, size_t ws_size,
                              hipStream_t stream) {
    const int*   rows  = (const int*)d_in[0];    // int32
    const int*   cols  = (const int*)d_in[1];    // int32
    const float* vals  = (const float*)d_in[2];  // fp32
    const float* uEmb  = (const float*)d_in[3];  // fp32
    const float* iEmb  = (const float*)d_in[4];  // fp32
    const float* Hyper = (const float*)d_in[5];  // fp32
    const float* zishi = (const float*)d_in[6];  // fp32
    // d_in[7] = keepRate (==1, static python branch) -> unused

    float* out = (float*)d_out;                  // fp32 output, [3, NN, DD]

    char* ws = (char*)d_ws;
    int2*  csr       = (int2*)(ws + 0);                 // 12,800,000
    int*   row_start = (int*)(ws + 12800000);           //    400,128 (padded)
    int*   counts    = (int*)(ws + 13600128);           //    400,000
    u16*   hyp       = (u16*)(ws + 14000128);           // 25,600,000
    u16*   cur       = (u16*)(ws + 39600128);           // 12,800,000
    float* lat       = (float*)(ws + 52400128);         //     32,768
    int*   bsum      = (int*)(ws + 52432896);           //      1,564 -> end 52,434,460

    // Scratch aliasing:
    //  out slab1 [25.6M, 38.4M): gate0 (bf16, 12.8 MB) — written k_hp_ah, last read
    //      k_fused_sl(l0); then k_hyperlat(l0) overwrites slab1 with hyperLat1.
    //  out slab2 [51.2M, 76.8M):
    //   ranks (int,  6.4 MB) @ [0, 6.4M):    written k_hp_ah, last read k_pos.
    //   pos   (int,  6.4 MB) @ [6.4M,12.8M): written k_pos,  last read k_fused0.
    //   gate1 (bf16, 12.8 MB) @ [0, 12.8M):  written k_hyperlat(l0 epilogue, after
    //                                        ranks/pos dead), last read k_lsp1.
    //   part  (fp32, 12.58 MB) @ [12.8M, 25.4M): written k_fused0/k_lsp1,
    //                                        last read k_fused_sl(l0)/k_latred.
    //  Final k_hyperlat(l=1) writes hyperLat2 over slab2 last (gate1+part dead).
    char*  slab2 = (char*)(out + (size_t)2 * NN * DD);
    u16*   gate0 = (u16*)(out + (size_t)1 * NN * DD);
    int*   ranks = (int*)slab2;
    int*   pos   = (int*)(slab2 + 6400000);
    u16*   gate1 = (u16*)slab2;
    float* part  = (float*)(slab2 + 12800000);

    // CSR build + embeds prep + gate0 + allhyper (fused)
    hipMemsetAsync(counts, 0, NN * sizeof(int), stream);
    k_hp_ah<<<2 * SCB, 256, 0, stream>>>(rows, counts, ranks,
                                         (const float4*)uEmb, (const float4*)iEmb,
                                         (ushort4*)cur, Hyper, hyp,
                                         (const float4*)zishi, (ushort4*)gate0);
    k_blocksum<<<NSB, 256, 0, stream>>>(counts, bsum);
    k_scanb<<<1, 512, 0, stream>>>(bsum);
    k_scanfinal<<<NSB, 256, 0, stream>>>(counts, bsum, row_start);
    k_pos<<<SCB, 256, 0, stream>>>(rows, ranks, row_start, pos);

    float* out0 = out;  // tem slab (layer-2 spmm overwrites it, matching reference)

    // ---- layer 0 ----
    k_fused0<<<LPB + SCB, 256, 0, stream>>>(pos, cols, vals, csr, cur, hyp, part);
    k_fused_sl<<<NN / 4 + 32, 256, 0, stream>>>(row_start, csr, gate0, out0, part, lat);
    k_hyperlat<<<NN / 16, 256, 0, stream>>>(hyp, lat, out0, out + (size_t)1 * NN * DD, cur,
                                            zishi, gate1, 1);   // emits gate1

    // ---- layer 1 ----
    k_lsp1<<<LPB + NN / 4, 256, 0, stream>>>(row_start, csr, gate1, out0, cur, hyp, part);
    k_latred<<<32, 256, 0, stream>>>(part, lat);
    k_hyperlat<<<NN / 16, 256, 0, stream>>>(hyp, lat, out0, out + (size_t)2 * NN * DD, cur,
                                            zishi, gate1, 0);
}

// Round 12
// 604.266 us; speedup vs baseline: 1.0514x; 1.0514x over previous
//
#include <hip/hip_runtime.h>
#include <hip/hip_bf16.h>

typedef unsigned short u16;

#define NN    100000     // total nodes
#define NU    50000      // users
#define DD    64         // latdim
#define HHY   128        // hyperNum
#define EE    1600000    // nnz
#define NCHK  384        // split-K chunks for lat (part = 12.58 MB, fits slab2 upper half)
#define CROWS 261        // ceil(NN/NCHK)
#define NSB   391        // ceil(NN/256) scan blocks
#define SCB   6250       // scatter / prep chunk count (EE/256)
#define LPB   768        // latpart flat blocks (NCHK chunks x 2 h-halves)
#define BUCKW 400000     // CSR bucket width in entries (EE/4) = 3.2 MB, fits per-XCD L2

__device__ __forceinline__ float us2f(u16 u) {
    union { unsigned int i; float f; } v; v.i = ((unsigned int)u) << 16; return v.f;
}
__device__ __forceinline__ u16 f2us(float f) {
    __hip_bfloat16 b = __float2bfloat16(f);
    return *reinterpret_cast<u16*>(&b);
}
__device__ __forceinline__ float lrelu(float x) { return x > 0.f ? x : 0.5f * x; }

// ================= device bodies (shared by fused wrappers) =================

// allhyper for 16 rows/block, Hyper staged in LDS, 2 rows per thread.
__device__ __forceinline__ void allhyper_body(int ab, float* hlds,
        const float4* __restrict__ u, const float4* __restrict__ it,
        const float* __restrict__ Hyper, u16* __restrict__ hyp) {
    int t = threadIdx.x;
    // stage Hyper[64][128] fp32 (2048 float4) into LDS, coalesced
    const float4* hsrc = (const float4*)Hyper;
    float4* hdst = (float4*)hlds;
#pragma unroll
    for (int i = 0; i < 8; i++) hdst[i * 256 + t] = hsrc[i * 256 + t];
    __syncthreads();
    int hg = t & 31;                       // 32 groups of 4 h
    int rs = t >> 5;                       // 8 row-pair slots
    int n0 = ab * 16 + rs * 2;             // rows n0, n0+1
    int n1 = n0 + 1;
    const float4* s0 = (n0 < NU) ? (u + (size_t)n0 * 16) : (it + (size_t)(n0 - NU) * 16);
    const float4* s1 = (n1 < NU) ? (u + (size_t)n1 * 16) : (it + (size_t)(n1 - NU) * 16);
    float a00 = 0.f, a01 = 0.f, a02 = 0.f, a03 = 0.f;
    float a10 = 0.f, a11 = 0.f, a12 = 0.f, a13 = 0.f;
#pragma unroll
    for (int half = 0; half < 2; half++) {
        float4 e0[8], e1[8];
#pragma unroll
        for (int i = 0; i < 8; i++) { e0[i] = s0[half * 8 + i]; e1[i] = s1[half * 8 + i]; }
#pragma unroll
        for (int i = 0; i < 8; i++) {
            float ev0[4] = { e0[i].x, e0[i].y, e0[i].z, e0[i].w };
            float ev1[4] = { e1[i].x, e1[i].y, e1[i].z, e1[i].w };
#pragma unroll
            for (int k = 0; k < 4; k++) {
                int d = half * 32 + i * 4 + k;
                float4 hq = *(const float4*)(hlds + d * HHY + hg * 4);
                a00 += ev0[k] * hq.x; a01 += ev0[k] * hq.y;
                a02 += ev0[k] * hq.z; a03 += ev0[k] * hq.w;
                a10 += ev1[k] * hq.x; a11 += ev1[k] * hq.y;
                a12 += ev1[k] * hq.z; a13 += ev1[k] * hq.w;
            }
        }
    }
    u16* o0 = hyp + (size_t)n0 * HHY + hg * 4;
    o0[0] = f2us(a00); o0[1] = f2us(a01); o0[2] = f2us(a02); o0[3] = f2us(a03);
    u16* o1 = hyp + (size_t)n1 * HHY + hg * 4;
    o1[0] = f2us(a10); o1[1] = f2us(a11); o1[2] = f2us(a12); o1[3] = f2us(a13);
}

// latpart: x4 n-unroll -> 20 independent loads in flight per thread (MLP)
__device__ __forceinline__ void latpart_body(int chunk, int yy,
        const u16* __restrict__ cur, const u16* __restrict__ hyp,
        float* __restrict__ part) {
    int t = threadIdx.x;
    int w = t >> 6, d = t & 63;
    int h0 = (yy * 4 + w) * 16;
    int c0 = chunk * CROWS;
    int c1 = c0 + CROWS; if (c1 > NN) c1 = NN;
    float acc[16];
#pragma unroll
    for (int j = 0; j < 16; j++) acc[j] = 0.f;
    int n = c0;
    for (; n + 4 <= c1; n += 4) {
        const u16* cp = cur + (size_t)n * DD + d;
        u16 ca = cp[0], cb = cp[DD], cc = cp[2 * DD], cd = cp[3 * DD];
        const ushort4* ha4 = (const ushort4*)(hyp + (size_t)n * HHY + h0);
        const ushort4* hb4 = (const ushort4*)(hyp + (size_t)(n + 1) * HHY + h0);
        const ushort4* hc4 = (const ushort4*)(hyp + (size_t)(n + 2) * HHY + h0);
        const ushort4* hd4 = (const ushort4*)(hyp + (size_t)(n + 3) * HHY + h0);
        u16 ua[16], ub[16], uc[16], ud[16];
        *(ushort4*)(ua + 0) = ha4[0]; *(ushort4*)(ua + 4) = ha4[1];
        *(ushort4*)(ua + 8) = ha4[2]; *(ushort4*)(ua + 12) = ha4[3];
        *(ushort4*)(ub + 0) = hb4[0]; *(ushort4*)(ub + 4) = hb4[1];
        *(ushort4*)(ub + 8) = hb4[2]; *(ushort4*)(ub + 12) = hb4[3];
        *(ushort4*)(uc + 0) = hc4[0]; *(ushort4*)(uc + 4) = hc4[1];
        *(ushort4*)(uc + 8) = hc4[2]; *(ushort4*)(uc + 12) = hc4[3];
        *(ushort4*)(ud + 0) = hd4[0]; *(ushort4*)(ud + 4) = hd4[1];
        *(ushort4*)(ud + 8) = hd4[2]; *(ushort4*)(ud + 12) = hd4[3];
        float fa = us2f(ca), fb = us2f(cb), fc = us2f(cc), fd = us2f(cd);
#pragma unroll
        for (int j = 0; j < 16; j++)
            acc[j] += us2f(ua[j]) * fa + us2f(ub[j]) * fb
                    + us2f(uc[j]) * fc + us2f(ud[j]) * fd;
    }
    for (; n < c1; n++) {
        float cv = us2f(cur[(size_t)n * DD + d]);
        const ushort4* hp = (const ushort4*)(hyp + (size_t)n * HHY + h0);
        u16 ha[16];
        *(ushort4*)(ha + 0)  = hp[0];
        *(ushort4*)(ha + 4)  = hp[1];
        *(ushort4*)(ha + 8)  = hp[2];
        *(ushort4*)(ha + 12) = hp[3];
#pragma unroll
        for (int j = 0; j < 16; j++) acc[j] += us2f(ha[j]) * cv;
    }
#pragma unroll
    for (int j = 0; j < 16; j++)
        part[((size_t)chunk * HHY + h0 + j) * DD + d] = acc[j];
}

// bucketed scatter: block handles (chunk, bucket); writes only edges whose CSR
// position falls in its bucket's 3.2 MB window (XCD-local L2 merging).
__device__ __forceinline__ void scatter_body(int chunk, int bucket,
        const int* __restrict__ pos,
        const int* __restrict__ cols, const float* __restrict__ vals,
        int2* __restrict__ csr) {
    int e = chunk * 256 + threadIdx.x;     // < EE
    int p = pos[e];
    if ((unsigned)p / (unsigned)BUCKW == (unsigned)bucket) {
        csr[p] = make_int2(cols[e], __float_as_int(vals[e]));
    }
}

__device__ __forceinline__ void spmm_body(int b,
        const int* __restrict__ row_start, const int2* __restrict__ csr,
        const u16* __restrict__ gate, float* __restrict__ out0) {
    int w = threadIdx.x >> 6, d = threadIdx.x & 63;
    int row = b * 4 + w;                   // b < NN/4 -> row < NN
    int s = row_start[row], e = row_start[row + 1];
    float a0 = 0.f, a1 = 0.f, a2 = 0.f, a3 = 0.f;
    float a4 = 0.f, a5 = 0.f, a6 = 0.f, a7 = 0.f;
    int j = s;
    for (; j + 8 <= e; j += 8) {
        int2 c0 = csr[j],     c1 = csr[j + 1], c2 = csr[j + 2], c3 = csr[j + 3];
        int2 c4 = csr[j + 4], c5 = csr[j + 5], c6 = csr[j + 6], c7 = csr[j + 7];
        float g0 = us2f(gate[(size_t)c0.x * DD + d]);
        float g1 = us2f(gate[(size_t)c1.x * DD + d]);
        float g2 = us2f(gate[(size_t)c2.x * DD + d]);
        float g3 = us2f(gate[(size_t)c3.x * DD + d]);
        float g4 = us2f(gate[(size_t)c4.x * DD + d]);
        float g5 = us2f(gate[(size_t)c5.x * DD + d]);
        float g6 = us2f(gate[(size_t)c6.x * DD + d]);
        float g7 = us2f(gate[(size_t)c7.x * DD + d]);
        a0 += __int_as_float(c0.y) * g0;
        a1 += __int_as_float(c1.y) * g1;
        a2 += __int_as_float(c2.y) * g2;
        a3 += __int_as_float(c3.y) * g3;
        a4 += __int_as_float(c4.y) * g4;
        a5 += __int_as_float(c5.y) * g5;
        a6 += __int_as_float(c6.y) * g6;
        a7 += __int_as_float(c7.y) * g7;
    }
    for (; j + 4 <= e; j += 4) {
        int2 c0 = csr[j], c1 = csr[j + 1], c2 = csr[j + 2], c3 = csr[j + 3];
        float g0 = us2f(gate[(size_t)c0.x * DD + d]);
        float g1 = us2f(gate[(size_t)c1.x * DD + d]);
        float g2 = us2f(gate[(size_t)c2.x * DD + d]);
        float g3 = us2f(gate[(size_t)c3.x * DD + d]);
        a0 += __int_as_float(c0.y) * g0;
        a1 += __int_as_float(c1.y) * g1;
        a2 += __int_as_float(c2.y) * g2;
        a3 += __int_as_float(c3.y) * g3;
    }
    for (; j < e; j++) {
        int2 cv = csr[j];
        a0 += __int_as_float(cv.y) * us2f(gate[(size_t)cv.x * DD + d]);
    }
    float acc = ((a0 + a1) + (a2 + a3)) + ((a4 + a5) + (a6 + a7));
    out0[(size_t)row * DD + d] = lrelu(acc);
}

__device__ __forceinline__ void latreduce_body(int lb,
        const float* __restrict__ part, float* __restrict__ lat) {
    int idx = lb * 256 + threadIdx.x;      // h*64+d, 8192 total
    float s0 = 0.f, s1 = 0.f, s2 = 0.f, s3 = 0.f;
    for (int c = 0; c < NCHK; c += 4) {
        s0 += part[(size_t)(c + 0) * HHY * DD + idx];
        s1 += part[(size_t)(c + 1) * HHY * DD + idx];
        s2 += part[(size_t)(c + 2) * HHY * DD + idx];
        s3 += part[(size_t)(c + 3) * HHY * DD + idx];
    }
    lat[idx] = lrelu((s0 + s1) + (s2 + s3));
}

// ================= kernels =================

// fused: prep (embeds0 -> bf16 cur AND gate0) + hist || allhyper (LDS-staged)
__global__ __launch_bounds__(256) void k_hp_ah(const int* __restrict__ rows,
                                               int* __restrict__ cnt,
                                               int* __restrict__ ranks,
                                               const float4* __restrict__ u,
                                               const float4* __restrict__ it,
                                               ushort4* __restrict__ cur,
                                               const float* __restrict__ Hyper,
                                               u16* __restrict__ hyp,
                                               const float4* __restrict__ z,
                                               ushort4* __restrict__ gate0) {
    __shared__ float hlds[DD * HHY];       // 32 KB (allhyper branch only)
    int bid = blockIdx.x;
    int p = bid & 1, q = bid >> 1;
    if (p == 0) {
        int e = q * 256 + threadIdx.x;     // < EE
        const int HALF = NU * DD / 4;      // 800000
        float4 f = (e < HALF) ? u[e] : it[e - HALF];
        ushort4 c; c.x = f2us(f.x); c.y = f2us(f.y); c.z = f2us(f.z); c.w = f2us(f.w);
        cur[e] = c;
        // gate0 = bf16( bf16(embeds0) * (2*sigmoid(z)-1) ), identical to old k_gate
        float4 zz = z[e];
        ushort4 g;
        g.x = f2us(us2f(c.x) * (2.f / (1.f + __expf(-zz.x)) - 1.f));
        g.y = f2us(us2f(c.y) * (2.f / (1.f + __expf(-zz.y)) - 1.f));
        g.z = f2us(us2f(c.z) * (2.f / (1.f + __expf(-zz.z)) - 1.f));
        g.w = f2us(us2f(c.w) * (2.f / (1.f + __expf(-zz.w)) - 1.f));
        gate0[e] = g;
        ranks[e] = atomicAdd(&cnt[rows[e]], 1);
    } else {
        allhyper_body(q, hlds, u, it, Hyper, hyp);
    }
}

// phase 1: per-block sums of cnt (256 counts per block)
__global__ __launch_bounds__(256) void k_blocksum(const int* __restrict__ cnt,
                                                  int* __restrict__ bsum) {
    __shared__ int s[256];
    int t = threadIdx.x;
    int i = blockIdx.x * 256 + t;
    s[t] = (i < NN) ? cnt[i] : 0;
    __syncthreads();
    for (int off = 128; off > 0; off >>= 1) {
        if (t < off) s[t] += s[t + off];
        __syncthreads();
    }
    if (t == 0) bsum[blockIdx.x] = s[0];
}

// phase 2: exclusive scan of the 391 block sums (single small block)
__global__ __launch_bounds__(512) void k_scanb(int* __restrict__ bsum) {
    __shared__ int s[512];
    int t = threadIdx.x;
    int v = (t < NSB) ? bsum[t] : 0;
    s[t] = v;
    __syncthreads();
    for (int off = 1; off < 512; off <<= 1) {
        int add = (t >= off) ? s[t - off] : 0;
        __syncthreads();
        s[t] += add;
        __syncthreads();
    }
    if (t < NSB) bsum[t] = s[t] - v;   // exclusive
}

// phase 3: block-local scan + block offset -> row_start
__global__ __launch_bounds__(256) void k_scanfinal(const int* __restrict__ cnt,
                                                   const int* __restrict__ bsum,
                                                   int* __restrict__ row_start) {
    __shared__ int s[256];
    int t = threadIdx.x;
    int i = blockIdx.x * 256 + t;
    int v = (i < NN) ? cnt[i] : 0;
    s[t] = v;
    __syncthreads();
    for (int off = 1; off < 256; off <<= 1) {
        int add = (t >= off) ? s[t - off] : 0;
        __syncthreads();
        s[t] += add;
        __syncthreads();
    }
    int excl = s[t] - v + bsum[blockIdx.x];
    if (i < NN) row_start[i] = excl;
    if (i == NN - 1) row_start[NN] = excl + v;   // total nnz
}

// pos[e] = final CSR position of edge e (coalesced; row_start gather is L2-resident)
__global__ __launch_bounds__(256) void k_pos(const int* __restrict__ rows,
                                             const int* __restrict__ ranks,
                                             const int* __restrict__ row_start,
                                             int* __restrict__ pos) {
    int e = blockIdx.x * 256 + threadIdx.x;   // grid = SCB -> e < EE
    pos[e] = row_start[rows[e]] + ranks[e];
}

// fused layer-0: latpart0 (first 768 long blocks) || XCD-bucketed scatter.
// Scatter block sid: xcd = sid%8 (HW round-robin), bucket = xcd&3,
// chunk = (sid/8)*2 + (xcd>>2). Each (chunk,bucket) covered exactly once;
// bucket b's 3.2MB CSR window is written only from XCDs {b, b+4}.
__global__ __launch_bounds__(256) void k_fused0(const int* __restrict__ pos,
                                                const int* __restrict__ cols,
                                                const float* __restrict__ vals,
                                                int2* __restrict__ csr,
                                                const u16* __restrict__ cur,
                                                const u16* __restrict__ hyp,
                                                float* __restrict__ part) {
    int bid = blockIdx.x;
    if (bid < LPB) {
        latpart_body(bid >> 1, bid & 1, cur, hyp, part);
    } else {
        int sid = bid - LPB;               // LPB%8==0 so sid%8 == bid%8 == XCD
        int xcd = sid & 7;
        int bucket = xcd & 3;
        int chunk = (sid >> 3) * 2 + (xcd >> 2);   // 0..6249
        scatter_body(chunk, bucket, pos, cols, vals, csr);
    }
}

// fused: latreduce (32 blocks, first) || spmm (25000 blocks)
__global__ __launch_bounds__(256) void k_fused_sl(const int* __restrict__ row_start,
                                                  const int2* __restrict__ csr,
                                                  const u16* __restrict__ gate,
                                                  float* __restrict__ out0,
                                                  const float* __restrict__ part,
                                                  float* __restrict__ lat) {
    int bid = blockIdx.x;
    if (bid < 32) latreduce_body(bid, part, lat);
    else          spmm_body(bid - 32, row_start, csr, gate, out0);
}

// layer-1 latpart standalone (gate1 is produced by k_hyperlat(l0) epilogue)
__global__ __launch_bounds__(256) void k_latpart1(const u16* __restrict__ cur,
                                                  const u16* __restrict__ hyp,
                                                  float* __restrict__ part) {
    int bid = blockIdx.x;                  // grid = LPB
    latpart_body(bid >> 1, bid & 1, cur, hyp, part);
}

// hyperLat = leaky(hyp @ lat); outL = hyperLat; cur = bf16(hyperLat + tem);
// if emit: gate = bf16(cur) * (2*sigmoid(z)-1)  (next layer's gate, fused epilogue)
__global__ __launch_bounds__(256) void k_hyperlat(const u16* __restrict__ hyp,
                                                  const float* __restrict__ lat,
                                                  const float* __restrict__ tem0,
                                                  float* __restrict__ outL,
                                                  u16* __restrict__ cur,
                                                  const float* __restrict__ z,
                                                  u16* __restrict__ gate,
                                                  int emit) {
    __shared__ float lds[HHY * DD];   // 32 KB
    int t = threadIdx.x;
    for (int i = t; i < HHY * DD; i += 256) lds[i] = lat[i];
    __syncthreads();
    int w = t >> 6, d = t & 63;
    int r0 = blockIdx.x * 16 + w * 4;
    float acc[4] = {0.f, 0.f, 0.f, 0.f};
    for (int h0 = 0; h0 < HHY; h0 += 8) {
        u16 hr[4][8];
#pragma unroll
        for (int r = 0; r < 4; r++) {
            const ushort4* pp = (const ushort4*)(hyp + (size_t)(r0 + r) * HHY + h0);
            ushort4 a = pp[0], b = pp[1];
            hr[r][0] = a.x; hr[r][1] = a.y; hr[r][2] = a.z; hr[r][3] = a.w;
            hr[r][4] = b.x; hr[r][5] = b.y; hr[r][6] = b.z; hr[r][7] = b.w;
        }
#pragma unroll
        for (int j = 0; j < 8; j++) {
            float lv = lds[(h0 + j) * DD + d];
#pragma unroll
            for (int r = 0; r < 4; r++) acc[r] += us2f(hr[r][j]) * lv;
        }
    }
#pragma unroll
    for (int r = 0; r < 4; r++) {
        size_t off = (size_t)(r0 + r) * DD + d;
        float hl = lrelu(acc[r]);
        float tem = tem0[off];
        u16 cb = f2us(hl + tem);
        outL[off] = hl;                 // fp32 output
        cur[off] = cb;                  // bf16 intermediate for next layer
        if (emit) {
            float zz = z[off];
            gate[off] = f2us(us2f(cb) * (2.f / (1.f + __expf(-zz)) - 1.f));
        }
    }
}

// ---------------- launch ----------------

extern "C" void kernel_launch(void* const* d_in, const int* in_sizes, int n_in,
                              void* d_out, int out_size, void* d_ws, size_t ws_size,
                              hipStream_t stream) {
    const int*   rows  = (const int*)d_in[0];    // int32
    const int*   cols  = (const int*)d_in[1];    // int32
    const float* vals  = (const float*)d_in[2];  // fp32
    const float* uEmb  = (const float*)d_in[3];  // fp32
    const float* iEmb  = (const float*)d_in[4];  // fp32
    const float* Hyper = (const float*)d_in[5];  // fp32
    const float* zishi = (const float*)d_in[6];  // fp32
    // d_in[7] = keepRate (==1, static python branch) -> unused

    float* out = (float*)d_out;                  // fp32 output, [3, NN, DD]

    char* ws = (char*)d_ws;
    int2*  csr       = (int2*)(ws + 0);                 // 12,800,000
    int*   row_start = (int*)(ws + 12800000);           //    400,128 (padded)
    int*   counts    = (int*)(ws + 13600128);           //    400,000
    u16*   hyp       = (u16*)(ws + 14000128);           // 25,600,000
    u16*   cur       = (u16*)(ws + 39600128);           // 12,800,000
    float* lat       = (float*)(ws + 52400128);         //     32,768
    int*   bsum      = (int*)(ws + 52432896);           //      1,564 -> end 52,434,460

    // Scratch aliasing:
    //  out slab1 [25.6M, 38.4M): gate0 (bf16, 12.8 MB) — written k_hp_ah, last read
    //      k_fused_sl(l0); then k_hyperlat(l0) overwrites slab1 with hyperLat1.
    //  out slab2 [51.2M, 76.8M):
    //   ranks (int,  6.4 MB) @ [0, 6.4M):    written k_hp_ah, last read k_pos.
    //   pos   (int,  6.4 MB) @ [6.4M,12.8M): written k_pos,  last read k_fused0.
    //   gate1 (bf16, 12.8 MB) @ [0, 12.8M):  written k_hyperlat(l0 epilogue, after
    //                                        ranks/pos dead), last read k_fused_sl(l1).
    //   part  (fp32, 12.58 MB) @ [12.8M, 25.4M): written k_fused0/k_latpart1,
    //                                        last read k_fused_sl of same layer.
    //  Final k_hyperlat(l=1) writes hyperLat2 over slab2 last (gate1+part dead).
    char*  slab2 = (char*)(out + (size_t)2 * NN * DD);
    u16*   gate0 = (u16*)(out + (size_t)1 * NN * DD);
    int*   ranks = (int*)slab2;
    int*   pos   = (int*)(slab2 + 6400000);
    u16*   gate1 = (u16*)slab2;
    float* part  = (float*)(slab2 + 12800000);

    // CSR build + embeds prep + gate0 + allhyper (fused)
    hipMemsetAsync(counts, 0, NN * sizeof(int), stream);
    k_hp_ah<<<2 * SCB, 256, 0, stream>>>(rows, counts, ranks,
                                         (const float4*)uEmb, (const float4*)iEmb,
                                         (ushort4*)cur, Hyper, hyp,
                                         (const float4*)zishi, (ushort4*)gate0);
    k_blocksum<<<NSB, 256, 0, stream>>>(counts, bsum);
    k_scanb<<<1, 512, 0, stream>>>(bsum);
    k_scanfinal<<<NSB, 256, 0, stream>>>(counts, bsum, row_start);
    k_pos<<<SCB, 256, 0, stream>>>(rows, ranks, row_start, pos);

    float* out0 = out;  // tem slab (layer-2 spmm overwrites it, matching reference)

    // ---- layer 0 ----
    k_fused0<<<LPB + 8 * 3125, 256, 0, stream>>>(pos, cols, vals, csr, cur, hyp, part);
    k_fused_sl<<<NN / 4 + 32, 256, 0, stream>>>(row_start, csr, gate0, out0, part, lat);
    k_hyperlat<<<NN / 16, 256, 0, stream>>>(hyp, lat, out0, out + (size_t)1 * NN * DD, cur,
                                            zishi, gate1, 1);   // emits gate1

    // ---- layer 1 ----
    k_latpart1<<<LPB, 256, 0, stream>>>(cur, hyp, part);
    k_fused_sl<<<NN / 4 + 32, 256, 0, stream>>>(row_start, csr, gate1, out0, part, lat);
    k_hyperlat<<<NN / 16, 256, 0, stream>>>(hyp, lat, out0, out + (size_t)2 * NN * DD, cur,
                                            zishi, gate1, 0);
}

// Round 13
// 527.263 us; speedup vs baseline: 1.2049x; 1.1460x over previous
//
#include <hip/hip_runtime.h>
#include <hip/hip_bf16.h>

typedef unsigned short u16;

#define NN    100000     // total nodes
#define NU    50000      // users
#define DD    64         // latdim
#define HHY   128        // hyperNum
#define EE    1600000    // nnz
#define NCHK  384        // split-K chunks for lat (part = 12.58 MB, fits slab2 upper half)
#define CROWS 261        // ceil(NN/NCHK)
#define NSB   391        // ceil(NN/256) scan blocks
#define SCB   6250       // scatter / prep chunk count (EE/256)
#define LPB   768        // latpart flat blocks (NCHK chunks x 2 h-halves)
#define BUCKW 400000     // CSR bucket width in entries (EE/4) = 3.2 MB, fits per-XCD L2

__device__ __forceinline__ float us2f(u16 u) {
    union { unsigned int i; float f; } v; v.i = ((unsigned int)u) << 16; return v.f;
}
__device__ __forceinline__ u16 f2us(float f) {
    __hip_bfloat16 b = __float2bfloat16(f);
    return *reinterpret_cast<u16*>(&b);
}
__device__ __forceinline__ float lrelu(float x) { return x > 0.f ? x : 0.5f * x; }

// ================= device bodies (shared by fused wrappers) =================

// allhyper for 16 rows/block, Hyper staged in LDS, 2 rows per thread.
__device__ __forceinline__ void allhyper_body(int ab, float* hlds,
        const float4* __restrict__ u, const float4* __restrict__ it,
        const float* __restrict__ Hyper, u16* __restrict__ hyp) {
    int t = threadIdx.x;
    // stage Hyper[64][128] fp32 (2048 float4) into LDS, coalesced
    const float4* hsrc = (const float4*)Hyper;
    float4* hdst = (float4*)hlds;
#pragma unroll
    for (int i = 0; i < 8; i++) hdst[i * 256 + t] = hsrc[i * 256 + t];
    __syncthreads();
    int hg = t & 31;                       // 32 groups of 4 h
    int rs = t >> 5;                       // 8 row-pair slots
    int n0 = ab * 16 + rs * 2;             // rows n0, n0+1
    int n1 = n0 + 1;
    const float4* s0 = (n0 < NU) ? (u + (size_t)n0 * 16) : (it + (size_t)(n0 - NU) * 16);
    const float4* s1 = (n1 < NU) ? (u + (size_t)n1 * 16) : (it + (size_t)(n1 - NU) * 16);
    float a00 = 0.f, a01 = 0.f, a02 = 0.f, a03 = 0.f;
    float a10 = 0.f, a11 = 0.f, a12 = 0.f, a13 = 0.f;
#pragma unroll
    for (int half = 0; half < 2; half++) {
        float4 e0[8], e1[8];
#pragma unroll
        for (int i = 0; i < 8; i++) { e0[i] = s0[half * 8 + i]; e1[i] = s1[half * 8 + i]; }
#pragma unroll
        for (int i = 0; i < 8; i++) {
            float ev0[4] = { e0[i].x, e0[i].y, e0[i].z, e0[i].w };
            float ev1[4] = { e1[i].x, e1[i].y, e1[i].z, e1[i].w };
#pragma unroll
            for (int k = 0; k < 4; k++) {
                int d = half * 32 + i * 4 + k;
                float4 hq = *(const float4*)(hlds + d * HHY + hg * 4);
                a00 += ev0[k] * hq.x; a01 += ev0[k] * hq.y;
                a02 += ev0[k] * hq.z; a03 += ev0[k] * hq.w;
                a10 += ev1[k] * hq.x; a11 += ev1[k] * hq.y;
                a12 += ev1[k] * hq.z; a13 += ev1[k] * hq.w;
            }
        }
    }
    u16* o0 = hyp + (size_t)n0 * HHY + hg * 4;
    o0[0] = f2us(a00); o0[1] = f2us(a01); o0[2] = f2us(a02); o0[3] = f2us(a03);
    u16* o1 = hyp + (size_t)n1 * HHY + hg * 4;
    o1[0] = f2us(a10); o1[1] = f2us(a11); o1[2] = f2us(a12); o1[3] = f2us(a13);
}

// latpart: x4 n-unroll -> 20 independent loads in flight per thread (MLP)
__device__ __forceinline__ void latpart_body(int chunk, int yy,
        const u16* __restrict__ cur, const u16* __restrict__ hyp,
        float* __restrict__ part) {
    int t = threadIdx.x;
    int w = t >> 6, d = t & 63;
    int h0 = (yy * 4 + w) * 16;
    int c0 = chunk * CROWS;
    int c1 = c0 + CROWS; if (c1 > NN) c1 = NN;
    float acc[16];
#pragma unroll
    for (int j = 0; j < 16; j++) acc[j] = 0.f;
    int n = c0;
    for (; n + 4 <= c1; n += 4) {
        const u16* cp = cur + (size_t)n * DD + d;
        u16 ca = cp[0], cb = cp[DD], cc = cp[2 * DD], cd = cp[3 * DD];
        const ushort4* ha4 = (const ushort4*)(hyp + (size_t)n * HHY + h0);
        const ushort4* hb4 = (const ushort4*)(hyp + (size_t)(n + 1) * HHY + h0);
        const ushort4* hc4 = (const ushort4*)(hyp + (size_t)(n + 2) * HHY + h0);
        const ushort4* hd4 = (const ushort4*)(hyp + (size_t)(n + 3) * HHY + h0);
        u16 ua[16], ub[16], uc[16], ud[16];
        *(ushort4*)(ua + 0) = ha4[0]; *(ushort4*)(ua + 4) = ha4[1];
        *(ushort4*)(ua + 8) = ha4[2]; *(ushort4*)(ua + 12) = ha4[3];
        *(ushort4*)(ub + 0) = hb4[0]; *(ushort4*)(ub + 4) = hb4[1];
        *(ushort4*)(ub + 8) = hb4[2]; *(ushort4*)(ub + 12) = hb4[3];
        *(ushort4*)(uc + 0) = hc4[0]; *(ushort4*)(uc + 4) = hc4[1];
        *(ushort4*)(uc + 8) = hc4[2]; *(ushort4*)(uc + 12) = hc4[3];
        *(ushort4*)(ud + 0) = hd4[0]; *(ushort4*)(ud + 4) = hd4[1];
        *(ushort4*)(ud + 8) = hd4[2]; *(ushort4*)(ud + 12) = hd4[3];
        float fa = us2f(ca), fb = us2f(cb), fc = us2f(cc), fd = us2f(cd);
#pragma unroll
        for (int j = 0; j < 16; j++)
            acc[j] += us2f(ua[j]) * fa + us2f(ub[j]) * fb
                    + us2f(uc[j]) * fc + us2f(ud[j]) * fd;
    }
    for (; n < c1; n++) {
        float cv = us2f(cur[(size_t)n * DD + d]);
        const ushort4* hp = (const ushort4*)(hyp + (size_t)n * HHY + h0);
        u16 ha[16];
        *(ushort4*)(ha + 0)  = hp[0];
        *(ushort4*)(ha + 4)  = hp[1];
        *(ushort4*)(ha + 8)  = hp[2];
        *(ushort4*)(ha + 12) = hp[3];
#pragma unroll
        for (int j = 0; j < 16; j++) acc[j] += us2f(ha[j]) * cv;
    }
#pragma unroll
    for (int j = 0; j < 16; j++)
        part[((size_t)chunk * HHY + h0 + j) * DD + d] = acc[j];
}

// bucketed scatter: block handles (chunk, bucket); writes only edges whose CSR
// position falls in its bucket's 3.2 MB window (XCD-local L2 merging).
__device__ __forceinline__ void scatter_body(int chunk, int bucket,
        const int* __restrict__ pos,
        const int* __restrict__ cols, const float* __restrict__ vals,
        int2* __restrict__ csr) {
    int e = chunk * 256 + threadIdx.x;     // < EE
    int p = pos[e];
    if ((unsigned)p / (unsigned)BUCKW == (unsigned)bucket) {
        csr[p] = make_int2(cols[e], __float_as_int(vals[e]));
    }
}

__device__ __forceinline__ void spmm_body(int b,
        const int* __restrict__ row_start, const int2* __restrict__ csr,
        const u16* __restrict__ gate, float* __restrict__ out0) {
    int w = threadIdx.x >> 6, d = threadIdx.x & 63;
    int row = b * 4 + w;                   // b < NN/4 -> row < NN
    int s = row_start[row], e = row_start[row + 1];
    float a0 = 0.f, a1 = 0.f, a2 = 0.f, a3 = 0.f;
    float a4 = 0.f, a5 = 0.f, a6 = 0.f, a7 = 0.f;
    int j = s;
    for (; j + 8 <= e; j += 8) {
        int2 c0 = csr[j],     c1 = csr[j + 1], c2 = csr[j + 2], c3 = csr[j + 3];
        int2 c4 = csr[j + 4], c5 = csr[j + 5], c6 = csr[j + 6], c7 = csr[j + 7];
        float g0 = us2f(gate[(size_t)c0.x * DD + d]);
        float g1 = us2f(gate[(size_t)c1.x * DD + d]);
        float g2 = us2f(gate[(size_t)c2.x * DD + d]);
        float g3 = us2f(gate[(size_t)c3.x * DD + d]);
        float g4 = us2f(gate[(size_t)c4.x * DD + d]);
        float g5 = us2f(gate[(size_t)c5.x * DD + d]);
        float g6 = us2f(gate[(size_t)c6.x * DD + d]);
        float g7 = us2f(gate[(size_t)c7.x * DD + d]);
        a0 += __int_as_float(c0.y) * g0;
        a1 += __int_as_float(c1.y) * g1;
        a2 += __int_as_float(c2.y) * g2;
        a3 += __int_as_float(c3.y) * g3;
        a4 += __int_as_float(c4.y) * g4;
        a5 += __int_as_float(c5.y) * g5;
        a6 += __int_as_float(c6.y) * g6;
        a7 += __int_as_float(c7.y) * g7;
    }
    for (; j + 4 <= e; j += 4) {
        int2 c0 = csr[j], c1 = csr[j + 1], c2 = csr[j + 2], c3 = csr[j + 3];
        float g0 = us2f(gate[(size_t)c0.x * DD + d]);
        float g1 = us2f(gate[(size_t)c1.x * DD + d]);
        float g2 = us2f(gate[(size_t)c2.x * DD + d]);
        float g3 = us2f(gate[(size_t)c3.x * DD + d]);
        a0 += __int_as_float(c0.y) * g0;
        a1 += __int_as_float(c1.y) * g1;
        a2 += __int_as_float(c2.y) * g2;
        a3 += __int_as_float(c3.y) * g3;
    }
    for (; j < e; j++) {
        int2 cv = csr[j];
        a0 += __int_as_float(cv.y) * us2f(gate[(size_t)cv.x * DD + d]);
    }
    float acc = ((a0 + a1) + (a2 + a3)) + ((a4 + a5) + (a6 + a7));
    out0[(size_t)row * DD + d] = lrelu(acc);
}

__device__ __forceinline__ void latreduce_body(int lb,
        const float* __restrict__ part, float* __restrict__ lat) {
    int idx = lb * 256 + threadIdx.x;      // h*64+d, 8192 total
    float s0 = 0.f, s1 = 0.f, s2 = 0.f, s3 = 0.f;
    for (int c = 0; c < NCHK; c += 4) {
        s0 += part[(size_t)(c + 0) * HHY * DD + idx];
        s1 += part[(size_t)(c + 1) * HHY * DD + idx];
        s2 += part[(size_t)(c + 2) * HHY * DD + idx];
        s3 += part[(size_t)(c + 3) * HHY * DD + idx];
    }
    lat[idx] = lrelu((s0 + s1) + (s2 + s3));
}

// ================= kernels =================

// fused: prep (embeds0 -> bf16 cur AND gate0) + hist || allhyper (LDS-staged)
__global__ __launch_bounds__(256) void k_hp_ah(const int* __restrict__ rows,
                                               int* __restrict__ cnt,
                                               int* __restrict__ ranks,
                                               const float4* __restrict__ u,
                                               const float4* __restrict__ it,
                                               ushort4* __restrict__ cur,
                                               const float* __restrict__ Hyper,
                                               u16* __restrict__ hyp,
                                               const float4* __restrict__ z,
                                               ushort4* __restrict__ gate0) {
    __shared__ float hlds[DD * HHY];       // 32 KB (allhyper branch only)
    int bid = blockIdx.x;
    int p = bid & 1, q = bid >> 1;
    if (p == 0) {
        int e = q * 256 + threadIdx.x;     // < EE
        const int HALF = NU * DD / 4;      // 800000
        float4 f = (e < HALF) ? u[e] : it[e - HALF];
        ushort4 c; c.x = f2us(f.x); c.y = f2us(f.y); c.z = f2us(f.z); c.w = f2us(f.w);
        cur[e] = c;
        // gate0 = bf16( bf16(embeds0) * (2*sigmoid(z)-1) ), identical to old k_gate
        float4 zz = z[e];
        ushort4 g;
        g.x = f2us(us2f(c.x) * (2.f / (1.f + __expf(-zz.x)) - 1.f));
        g.y = f2us(us2f(c.y) * (2.f / (1.f + __expf(-zz.y)) - 1.f));
        g.z = f2us(us2f(c.z) * (2.f / (1.f + __expf(-zz.z)) - 1.f));
        g.w = f2us(us2f(c.w) * (2.f / (1.f + __expf(-zz.w)) - 1.f));
        gate0[e] = g;
        ranks[e] = atomicAdd(&cnt[rows[e]], 1);
    } else {
        allhyper_body(q, hlds, u, it, Hyper, hyp);
    }
}

// phase 1: per-block sums of cnt (256 counts per block)
__global__ __launch_bounds__(256) void k_blocksum(const int* __restrict__ cnt,
                                                  int* __restrict__ bsum) {
    __shared__ int s[256];
    int t = threadIdx.x;
    int i = blockIdx.x * 256 + t;
    s[t] = (i < NN) ? cnt[i] : 0;
    __syncthreads();
    for (int off = 128; off > 0; off >>= 1) {
        if (t < off) s[t] += s[t + off];
        __syncthreads();
    }
    if (t == 0) bsum[blockIdx.x] = s[0];
}

// phase 2: exclusive scan of the 391 block sums (single small block)
__global__ __launch_bounds__(512) void k_scanb(int* __restrict__ bsum) {
    __shared__ int s[512];
    int t = threadIdx.x;
    int v = (t < NSB) ? bsum[t] : 0;
    s[t] = v;
    __syncthreads();
    for (int off = 1; off < 512; off <<= 1) {
        int add = (t >= off) ? s[t - off] : 0;
        __syncthreads();
        s[t] += add;
        __syncthreads();
    }
    if (t < NSB) bsum[t] = s[t] - v;   // exclusive
}

// phase 3: block-local scan + block offset -> row_start
__global__ __launch_bounds__(256) void k_scanfinal(const int* __restrict__ cnt,
                                                   const int* __restrict__ bsum,
                                                   int* __restrict__ row_start) {
    __shared__ int s[256];
    int t = threadIdx.x;
    int i = blockIdx.x * 256 + t;
    int v = (i < NN) ? cnt[i] : 0;
    s[t] = v;
    __syncthreads();
    for (int off = 1; off < 256; off <<= 1) {
        int add = (t >= off) ? s[t - off] : 0;
        __syncthreads();
        s[t] += add;
        __syncthreads();
    }
    int excl = s[t] - v + bsum[blockIdx.x];
    if (i < NN) row_start[i] = excl;
    if (i == NN - 1) row_start[NN] = excl + v;   // total nnz
}

// pos[e] = final CSR position of edge e (coalesced; row_start gather is L2-resident)
__global__ __launch_bounds__(256) void k_pos(const int* __restrict__ rows,
                                             const int* __restrict__ ranks,
                                             const int* __restrict__ row_start,
                                             int* __restrict__ pos) {
    int e = blockIdx.x * 256 + threadIdx.x;   // grid = SCB -> e < EE
    pos[e] = row_start[rows[e]] + ranks[e];
}

// fused layer-0: latpart0 (first 768 long blocks) || XCD-bucketed scatter.
__global__ __launch_bounds__(256) void k_fused0(const int* __restrict__ pos,
                                                const int* __restrict__ cols,
                                                const float* __restrict__ vals,
                                                int2* __restrict__ csr,
                                                const u16* __restrict__ cur,
                                                const u16* __restrict__ hyp,
                                                float* __restrict__ part) {
    int bid = blockIdx.x;
    if (bid < LPB) {
        latpart_body(bid >> 1, bid & 1, cur, hyp, part);
    } else {
        int sid = bid - LPB;               // LPB%8==0 so sid%8 == bid%8 == XCD
        int xcd = sid & 7;
        int bucket = xcd & 3;
        int chunk = (sid >> 3) * 2 + (xcd >> 2);   // 0..6249
        scatter_body(chunk, bucket, pos, cols, vals, csr);
    }
}

// fused: latreduce (32 blocks, first) || spmm (25000 blocks)
__global__ __launch_bounds__(256) void k_fused_sl(const int* __restrict__ row_start,
                                                  const int2* __restrict__ csr,
                                                  const u16* __restrict__ gate,
                                                  float* __restrict__ out0,
                                                  const float* __restrict__ part,
                                                  float* __restrict__ lat) {
    int bid = blockIdx.x;
    if (bid < 32) latreduce_body(bid, part, lat);
    else          spmm_body(bid - 32, row_start, csr, gate, out0);
}

// layer-1 latpart standalone (gate1 is produced by k_hyperlat(l0) epilogue)
__global__ __launch_bounds__(256) void k_latpart1(const u16* __restrict__ cur,
                                                  const u16* __restrict__ hyp,
                                                  float* __restrict__ part) {
    int bid = blockIdx.x;                  // grid = LPB
    latpart_body(bid >> 1, bid & 1, cur, hyp, part);
}

// hyperLat = leaky(hyp @ lat); outL = hyperLat; cur = bf16(hyperLat + tem);
// if emit: gate = bf16(cur) * (2*sigmoid(z)-1).
// Lane mapping: lane = row_local*4 + d_quad -> each lane does 1 row x 4 d.
// LDS read becomes float4 (ds_read_b128) with 16-lane same-address broadcast
// (free per bank rules) -> 4x fewer LDS instrs, each broadcast-cheap.
// Accumulation order over h unchanged -> bit-identical to previous version.
__global__ __launch_bounds__(256) void k_hyperlat(const u16* __restrict__ hyp,
                                                  const float* __restrict__ lat,
                                                  const float* __restrict__ tem0,
                                                  float* __restrict__ outL,
                                                  u16* __restrict__ cur,
                                                  const float* __restrict__ z,
                                                  u16* __restrict__ gate,
                                                  int emit) {
    __shared__ float lds[HHY * DD];   // 32 KB
    int t = threadIdx.x;
    for (int i = t; i < HHY * DD / 4; i += 256)
        ((float4*)lds)[i] = ((const float4*)lat)[i];
    __syncthreads();
    int w = t >> 6, l = t & 63;
    int rl = l >> 2, dq = l & 3;
    int r = blockIdx.x * 16 + rl;          // 16 rows per block
    int d0 = w * 16 + dq * 4;              // wave covers 16 d, lane 4 consecutive d
    float a0 = 0.f, a1 = 0.f, a2 = 0.f, a3 = 0.f;
    const u16* hrow = hyp + (size_t)r * HHY;
    for (int h0 = 0; h0 < HHY; h0 += 8) {
        ushort4 p0 = *(const ushort4*)(hrow + h0);
        ushort4 p1 = *(const ushort4*)(hrow + h0 + 4);
        u16 hv[8] = { p0.x, p0.y, p0.z, p0.w, p1.x, p1.y, p1.z, p1.w };
#pragma unroll
        for (int j = 0; j < 8; j++) {
            float hvf = us2f(hv[j]);
            float4 lv = *(const float4*)(lds + (h0 + j) * DD + d0);
            a0 += hvf * lv.x; a1 += hvf * lv.y;
            a2 += hvf * lv.z; a3 += hvf * lv.w;
        }
    }
    size_t off = (size_t)r * DD + d0;
    float h0_ = lrelu(a0), h1_ = lrelu(a1), h2_ = lrelu(a2), h3_ = lrelu(a3);
    float4 tem = *(const float4*)(tem0 + off);
    *(float4*)(outL + off) = make_float4(h0_, h1_, h2_, h3_);
    ushort4 cb;
    cb.x = f2us(h0_ + tem.x); cb.y = f2us(h1_ + tem.y);
    cb.z = f2us(h2_ + tem.z); cb.w = f2us(h3_ + tem.w);
    *(ushort4*)(cur + off) = cb;
    if (emit) {
        float4 zz = *(const float4*)(z + off);
        ushort4 g;
        g.x = f2us(us2f(cb.x) * (2.f / (1.f + __expf(-zz.x)) - 1.f));
        g.y = f2us(us2f(cb.y) * (2.f / (1.f + __expf(-zz.y)) - 1.f));
        g.z = f2us(us2f(cb.z) * (2.f / (1.f + __expf(-zz.z)) - 1.f));
        g.w = f2us(us2f(cb.w) * (2.f / (1.f + __expf(-zz.w)) - 1.f));
        *(ushort4*)(gate + off) = g;
    }
}

// ---------------- launch ----------------

extern "C" void kernel_launch(void* const* d_in, const int* in_sizes, int n_in,
                              void* d_out, int out_size, void* d_ws, size_t ws_size,
                              hipStream_t stream) {
    const int*   rows  = (const int*)d_in[0];    // int32
    const int*   cols  = (const int*)d_in[1];    // int32
    const float* vals  = (const float*)d_in[2];  // fp32
    const float* uEmb  = (const float*)d_in[3];  // fp32
    const float* iEmb  = (const float*)d_in[4];  // fp32
    const float* Hyper = (const float*)d_in[5];  // fp32
    const float* zishi = (const float*)d_in[6];  // fp32
    // d_in[7] = keepRate (==1, static python branch) -> unused

    float* out = (float*)d_out;                  // fp32 output, [3, NN, DD]

    char* ws = (char*)d_ws;
    int2*  csr       = (int2*)(ws + 0);                 // 12,800,000
    int*   row_start = (int*)(ws + 12800000);           //    400,128 (padded)
    int*   counts    = (int*)(ws + 13600128);           //    400,000
    u16*   hyp       = (u16*)(ws + 14000128);           // 25,600,000
    u16*   cur       = (u16*)(ws + 39600128);           // 12,800,000
    float* lat       = (float*)(ws + 52400128);         //     32,768
    int*   bsum      = (int*)(ws + 52432896);           //      1,564 -> end 52,434,460

    // Scratch aliasing:
    //  out slab1 [25.6M, 38.4M): gate0 (bf16, 12.8 MB) — written k_hp_ah, last read
    //      k_fused_sl(l0); then k_hyperlat(l0) overwrites slab1 with hyperLat1.
    //  out slab2 [51.2M, 76.8M):
    //   ranks (int,  6.4 MB) @ [0, 6.4M):    written k_hp_ah, last read k_pos.
    //   pos   (int,  6.4 MB) @ [6.4M,12.8M): written k_pos,  last read k_fused0.
    //   gate1 (bf16, 12.8 MB) @ [0, 12.8M):  written k_hyperlat(l0 epilogue, after
    //                                        ranks/pos dead), last read k_fused_sl(l1).
    //   part  (fp32, 12.58 MB) @ [12.8M, 25.4M): written k_fused0/k_latpart1,
    //                                        last read k_fused_sl of same layer.
    //  Final k_hyperlat(l=1) writes hyperLat2 over slab2 last (gate1+part dead).
    char*  slab2 = (char*)(out + (size_t)2 * NN * DD);
    u16*   gate0 = (u16*)(out + (size_t)1 * NN * DD);
    int*   ranks = (int*)slab2;
    int*   pos   = (int*)(slab2 + 6400000);
    u16*   gate1 = (u16*)slab2;
    float* part  = (float*)(slab2 + 12800000);

    // CSR build + embeds prep + gate0 + allhyper (fused)
    hipMemsetAsync(counts, 0, NN * sizeof(int), stream);
    k_hp_ah<<<2 * SCB, 256, 0, stream>>>(rows, counts, ranks,
                                         (const float4*)uEmb, (const float4*)iEmb,
                                         (ushort4*)cur, Hyper, hyp,
                                         (const float4*)zishi, (ushort4*)gate0);
    k_blocksum<<<NSB, 256, 0, stream>>>(counts, bsum);
    k_scanb<<<1, 512, 0, stream>>>(bsum);
    k_scanfinal<<<NSB, 256, 0, stream>>>(counts, bsum, row_start);
    k_pos<<<SCB, 256, 0, stream>>>(rows, ranks, row_start, pos);

    float* out0 = out;  // tem slab (layer-2 spmm overwrites it, matching reference)

    // ---- layer 0 ----
    k_fused0<<<LPB + 8 * 3125, 256, 0, stream>>>(pos, cols, vals, csr, cur, hyp, part);
    k_fused_sl<<<NN / 4 + 32, 256, 0, stream>>>(row_start, csr, gate0, out0, part, lat);
    k_hyperlat<<<NN / 16, 256, 0, stream>>>(hyp, lat, out0, out + (size_t)1 * NN * DD, cur,
                                            zishi, gate1, 1);   // emits gate1

    // ---- layer 1 ----
    k_latpart1<<<LPB, 256, 0, stream>>>(cur, hyp, part);
    k_fused_sl<<<NN / 4 + 32, 256, 0, stream>>>(row_start, csr, gate1, out0, part, lat);
    k_hyperlat<<<NN / 16, 256, 0, stream>>>(hyp, lat, out0, out + (size_t)2 * NN * DD, cur,
                                            zishi, gate1, 0);
}

// Round 14
// 445.815 us; speedup vs baseline: 1.4250x; 1.1827x over previous
//
#include <hip/hip_runtime.h>
#include <hip/hip_bf16.h>

typedef unsigned short u16;
typedef short bf16x8 __attribute__((ext_vector_type(8)));   // 8 bf16 (4 VGPRs)
typedef float f32x4 __attribute__((ext_vector_type(4)));    // 4 fp32 acc

#define NN    100000     // total nodes
#define NU    50000      // users
#define DD    64         // latdim
#define HHY   128        // hyperNum
#define EE    1600000    // nnz
#define NCHK  352        // split-K chunks (multiple of 4; part = 11.53 MB fits slab)
#define CROWS 288        // rows per chunk (multiple of 32 -> clean MFMA K-steps)
#define NSB   391        // ceil(NN/256) scan blocks
#define SCB   6250       // scatter / prep chunk count (EE/256)
#define LPB   704        // latpart blocks = NCHK*2 halves (multiple of 8 for XCD math)
#define BUCKW 400000     // CSR bucket width in entries (EE/4) = 3.2 MB, fits per-XCD L2

__device__ __forceinline__ float us2f(u16 u) {
    union { unsigned int i; float f; } v; v.i = ((unsigned int)u) << 16; return v.f;
}
__device__ __forceinline__ u16 f2us(float f) {
    __hip_bfloat16 b = __float2bfloat16(f);
    return *reinterpret_cast<u16*>(&b);
}
__device__ __forceinline__ float lrelu(float x) { return x > 0.f ? x : 0.5f * x; }

// ================= device bodies =================

// allhyper for 16 rows/block, Hyper staged in LDS, 2 rows per thread.
__device__ __forceinline__ void allhyper_body(int ab, float* hlds,
        const float4* __restrict__ u, const float4* __restrict__ it,
        const float* __restrict__ Hyper, u16* __restrict__ hyp) {
    int t = threadIdx.x;
    const float4* hsrc = (const float4*)Hyper;
    float4* hdst = (float4*)hlds;
#pragma unroll
    for (int i = 0; i < 8; i++) hdst[i * 256 + t] = hsrc[i * 256 + t];
    __syncthreads();
    int hg = t & 31;                       // 32 groups of 4 h
    int rs = t >> 5;                       // 8 row-pair slots
    int n0 = ab * 16 + rs * 2;
    int n1 = n0 + 1;
    const float4* s0 = (n0 < NU) ? (u + (size_t)n0 * 16) : (it + (size_t)(n0 - NU) * 16);
    const float4* s1 = (n1 < NU) ? (u + (size_t)n1 * 16) : (it + (size_t)(n1 - NU) * 16);
    float a00 = 0.f, a01 = 0.f, a02 = 0.f, a03 = 0.f;
    float a10 = 0.f, a11 = 0.f, a12 = 0.f, a13 = 0.f;
#pragma unroll
    for (int half = 0; half < 2; half++) {
        float4 e0[8], e1[8];
#pragma unroll
        for (int i = 0; i < 8; i++) { e0[i] = s0[half * 8 + i]; e1[i] = s1[half * 8 + i]; }
#pragma unroll
        for (int i = 0; i < 8; i++) {
            float ev0[4] = { e0[i].x, e0[i].y, e0[i].z, e0[i].w };
            float ev1[4] = { e1[i].x, e1[i].y, e1[i].z, e1[i].w };
#pragma unroll
            for (int k = 0; k < 4; k++) {
                int d = half * 32 + i * 4 + k;
                float4 hq = *(const float4*)(hlds + d * HHY + hg * 4);
                a00 += ev0[k] * hq.x; a01 += ev0[k] * hq.y;
                a02 += ev0[k] * hq.z; a03 += ev0[k] * hq.w;
                a10 += ev1[k] * hq.x; a11 += ev1[k] * hq.y;
                a12 += ev1[k] * hq.z; a13 += ev1[k] * hq.w;
            }
        }
    }
    u16* o0 = hyp + (size_t)n0 * HHY + hg * 4;
    o0[0] = f2us(a00); o0[1] = f2us(a01); o0[2] = f2us(a02); o0[3] = f2us(a03);
    u16* o1 = hyp + (size_t)n1 * HHY + hg * 4;
    o1[0] = f2us(a10); o1[1] = f2us(a11); o1[2] = f2us(a12); o1[3] = f2us(a13);
}

// latpart via MFMA: part[chunk][h][d] = sum_{n in chunk} hyp[n][h]*cur[n][d].
// Block (256 thr, 4 waves) owns (chunk, half=64 h). Per 32-row K-step:
// stage cur[32][64] + hyp[32][64] to LDS (stride 68 u16: 2-way banks, b64-aligned),
// wave w -> A-frag (h tile = half*64 + w*16), 4 B-frags (d tiles), 4 MFMAs.
// Frag maps (m89-verified C/D; standard A/B): A[r=l&15 -> h][k=(l>>4)*8+j],
// B[k][c=l&15 -> d], C col=lane&15 (d), row=(lane>>4)*4+q (h).
__device__ __forceinline__ void latpart_mfma(int chunk, int half,
        const u16* __restrict__ cur_g, const u16* __restrict__ hyp_g,
        float* __restrict__ part, u16* sc, u16* sh) {
    int t = threadIdx.x;
    int w = t >> 6, l = t & 63;
    int r = l & 15, kb = l >> 4;
    int hbase = half * 64;
    int c0 = chunk * CROWS;
    int c1 = c0 + CROWS; if (c1 > NN) c1 = NN;
    f32x4 acc0 = {0.f, 0.f, 0.f, 0.f};
    f32x4 acc1 = acc0, acc2 = acc0, acc3 = acc0;
    int srow = t >> 3, scol = (t & 7) * 8;
    for (int n0 = c0; n0 < c1; n0 += 32) {      // c0/c1 multiples of 32 within NN
        const u16* cg = cur_g + (size_t)(n0 + srow) * DD + scol;
        const u16* hg = hyp_g + (size_t)(n0 + srow) * HHY + hbase + scol;
        *(ushort4*)(sc + srow * 68 + scol)     = *(const ushort4*)(cg);
        *(ushort4*)(sc + srow * 68 + scol + 4) = *(const ushort4*)(cg + 4);
        *(ushort4*)(sh + srow * 68 + scol)     = *(const ushort4*)(hg);
        *(ushort4*)(sh + srow * 68 + scol + 4) = *(const ushort4*)(hg + 4);
        __syncthreads();
        bf16x8 a;
#pragma unroll
        for (int j = 0; j < 8; j++)
            a[j] = (short)sh[(kb * 8 + j) * 68 + w * 16 + r];
        bf16x8 b0, b1, b2, b3;
#pragma unroll
        for (int j = 0; j < 8; j++) {
            int ro = (kb * 8 + j) * 68 + r;
            b0[j] = (short)sc[ro];
            b1[j] = (short)sc[ro + 16];
            b2[j] = (short)sc[ro + 32];
            b3[j] = (short)sc[ro + 48];
        }
        acc0 = __builtin_amdgcn_mfma_f32_16x16x32_bf16(a, b0, acc0, 0, 0, 0);
        acc1 = __builtin_amdgcn_mfma_f32_16x16x32_bf16(a, b1, acc1, 0, 0, 0);
        acc2 = __builtin_amdgcn_mfma_f32_16x16x32_bf16(a, b2, acc2, 0, 0, 0);
        acc3 = __builtin_amdgcn_mfma_f32_16x16x32_bf16(a, b3, acc3, 0, 0, 0);
        __syncthreads();
    }
    size_t base = ((size_t)chunk * HHY + hbase + w * 16 + kb * 4) * DD + r;
#pragma unroll
    for (int q = 0; q < 4; q++) {
        float* p = part + base + (size_t)q * DD;   // h advances with q
        p[0]  = acc0[q];
        p[16] = acc1[q];
        p[32] = acc2[q];
        p[48] = acc3[q];
    }
}

// bucketed scatter: block handles (chunk, bucket); writes only edges whose CSR
// position falls in its bucket's 3.2 MB window (XCD-local L2 merging).
__device__ __forceinline__ void scatter_body(int chunk, int bucket,
        const int* __restrict__ pos,
        const int* __restrict__ cols, const float* __restrict__ vals,
        int2* __restrict__ csr) {
    int e = chunk * 256 + threadIdx.x;     // < EE
    int p = pos[e];
    if ((unsigned)p / (unsigned)BUCKW == (unsigned)bucket) {
        csr[p] = make_int2(cols[e], __float_as_int(vals[e]));
    }
}

__device__ __forceinline__ void spmm_body(int b,
        const int* __restrict__ row_start, const int2* __restrict__ csr,
        const u16* __restrict__ gate, float* __restrict__ out0) {
    int w = threadIdx.x >> 6, d = threadIdx.x & 63;
    int row = b * 4 + w;                   // b < NN/4 -> row < NN
    int s = row_start[row], e = row_start[row + 1];
    float a0 = 0.f, a1 = 0.f, a2 = 0.f, a3 = 0.f;
    float a4 = 0.f, a5 = 0.f, a6 = 0.f, a7 = 0.f;
    int j = s;
    for (; j + 8 <= e; j += 8) {
        int2 c0 = csr[j],     c1 = csr[j + 1], c2 = csr[j + 2], c3 = csr[j + 3];
        int2 c4 = csr[j + 4], c5 = csr[j + 5], c6 = csr[j + 6], c7 = csr[j + 7];
        float g0 = us2f(gate[(size_t)c0.x * DD + d]);
        float g1 = us2f(gate[(size_t)c1.x * DD + d]);
        float g2 = us2f(gate[(size_t)c2.x * DD + d]);
        float g3 = us2f(gate[(size_t)c3.x * DD + d]);
        float g4 = us2f(gate[(size_t)c4.x * DD + d]);
        float g5 = us2f(gate[(size_t)c5.x * DD + d]);
        float g6 = us2f(gate[(size_t)c6.x * DD + d]);
        float g7 = us2f(gate[(size_t)c7.x * DD + d]);
        a0 += __int_as_float(c0.y) * g0;
        a1 += __int_as_float(c1.y) * g1;
        a2 += __int_as_float(c2.y) * g2;
        a3 += __int_as_float(c3.y) * g3;
        a4 += __int_as_float(c4.y) * g4;
        a5 += __int_as_float(c5.y) * g5;
        a6 += __int_as_float(c6.y) * g6;
        a7 += __int_as_float(c7.y) * g7;
    }
    for (; j + 4 <= e; j += 4) {
        int2 c0 = csr[j], c1 = csr[j + 1], c2 = csr[j + 2], c3 = csr[j + 3];
        float g0 = us2f(gate[(size_t)c0.x * DD + d]);
        float g1 = us2f(gate[(size_t)c1.x * DD + d]);
        float g2 = us2f(gate[(size_t)c2.x * DD + d]);
        float g3 = us2f(gate[(size_t)c3.x * DD + d]);
        a0 += __int_as_float(c0.y) * g0;
        a1 += __int_as_float(c1.y) * g1;
        a2 += __int_as_float(c2.y) * g2;
        a3 += __int_as_float(c3.y) * g3;
    }
    for (; j < e; j++) {
        int2 cv = csr[j];
        a0 += __int_as_float(cv.y) * us2f(gate[(size_t)cv.x * DD + d]);
    }
    float acc = ((a0 + a1) + (a2 + a3)) + ((a4 + a5) + (a6 + a7));
    out0[(size_t)row * DD + d] = lrelu(acc);
}

__device__ __forceinline__ void latreduce_body(int lb,
        const float* __restrict__ part, float* __restrict__ lat) {
    int idx = lb * 256 + threadIdx.x;      // h*64+d, 8192 total
    float s0 = 0.f, s1 = 0.f, s2 = 0.f, s3 = 0.f;
    for (int c = 0; c < NCHK; c += 4) {
        s0 += part[(size_t)(c + 0) * HHY * DD + idx];
        s1 += part[(size_t)(c + 1) * HHY * DD + idx];
        s2 += part[(size_t)(c + 2) * HHY * DD + idx];
        s3 += part[(size_t)(c + 3) * HHY * DD + idx];
    }
    lat[idx] = lrelu((s0 + s1) + (s2 + s3));
}

// ================= kernels =================

// fused: prep (embeds0 -> bf16 cur AND gate0) + hist || allhyper (LDS-staged)
__global__ __launch_bounds__(256) void k_hp_ah(const int* __restrict__ rows,
                                               int* __restrict__ cnt,
                                               int* __restrict__ ranks,
                                               const float4* __restrict__ u,
                                               const float4* __restrict__ it,
                                               ushort4* __restrict__ cur,
                                               const float* __restrict__ Hyper,
                                               u16* __restrict__ hyp,
                                               const float4* __restrict__ z,
                                               ushort4* __restrict__ gate0) {
    __shared__ float hlds[DD * HHY];       // 32 KB (allhyper branch only)
    int bid = blockIdx.x;
    int p = bid & 1, q = bid >> 1;
    if (p == 0) {
        int e = q * 256 + threadIdx.x;     // < EE
        const int HALF = NU * DD / 4;      // 800000
        float4 f = (e < HALF) ? u[e] : it[e - HALF];
        ushort4 c; c.x = f2us(f.x); c.y = f2us(f.y); c.z = f2us(f.z); c.w = f2us(f.w);
        cur[e] = c;
        float4 zz = z[e];
        ushort4 g;
        g.x = f2us(us2f(c.x) * (2.f / (1.f + __expf(-zz.x)) - 1.f));
        g.y = f2us(us2f(c.y) * (2.f / (1.f + __expf(-zz.y)) - 1.f));
        g.z = f2us(us2f(c.z) * (2.f / (1.f + __expf(-zz.z)) - 1.f));
        g.w = f2us(us2f(c.w) * (2.f / (1.f + __expf(-zz.w)) - 1.f));
        gate0[e] = g;
        ranks[e] = atomicAdd(&cnt[rows[e]], 1);
    } else {
        allhyper_body(q, hlds, u, it, Hyper, hyp);
    }
}

// phase 1: per-block sums of cnt
__global__ __launch_bounds__(256) void k_blocksum(const int* __restrict__ cnt,
                                                  int* __restrict__ bsum) {
    __shared__ int s[256];
    int t = threadIdx.x;
    int i = blockIdx.x * 256 + t;
    s[t] = (i < NN) ? cnt[i] : 0;
    __syncthreads();
    for (int off = 128; off > 0; off >>= 1) {
        if (t < off) s[t] += s[t + off];
        __syncthreads();
    }
    if (t == 0) bsum[blockIdx.x] = s[0];
}

// phase 2: exclusive scan of the 391 block sums
__global__ __launch_bounds__(512) void k_scanb(int* __restrict__ bsum) {
    __shared__ int s[512];
    int t = threadIdx.x;
    int v = (t < NSB) ? bsum[t] : 0;
    s[t] = v;
    __syncthreads();
    for (int off = 1; off < 512; off <<= 1) {
        int add = (t >= off) ? s[t - off] : 0;
        __syncthreads();
        s[t] += add;
        __syncthreads();
    }
    if (t < NSB) bsum[t] = s[t] - v;   // exclusive
}

// phase 3: block-local scan + block offset -> row_start
__global__ __launch_bounds__(256) void k_scanfinal(const int* __restrict__ cnt,
                                                   const int* __restrict__ bsum,
                                                   int* __restrict__ row_start) {
    __shared__ int s[256];
    int t = threadIdx.x;
    int i = blockIdx.x * 256 + t;
    int v = (i < NN) ? cnt[i] : 0;
    s[t] = v;
    __syncthreads();
    for (int off = 1; off < 256; off <<= 1) {
        int add = (t >= off) ? s[t - off] : 0;
        __syncthreads();
        s[t] += add;
        __syncthreads();
    }
    int excl = s[t] - v + bsum[blockIdx.x];
    if (i < NN) row_start[i] = excl;
    if (i == NN - 1) row_start[NN] = excl + v;   // total nnz
}

// pos[e] = final CSR position of edge e
__global__ __launch_bounds__(256) void k_pos(const int* __restrict__ rows,
                                             const int* __restrict__ ranks,
                                             const int* __restrict__ row_start,
                                             int* __restrict__ pos) {
    int e = blockIdx.x * 256 + threadIdx.x;   // grid = SCB -> e < EE
    pos[e] = row_start[rows[e]] + ranks[e];
}

// fused layer-0: MFMA latpart0 (first LPB blocks) || XCD-bucketed scatter.
__global__ __launch_bounds__(256) void k_fused0(const int* __restrict__ pos,
                                                const int* __restrict__ cols,
                                                const float* __restrict__ vals,
                                                int2* __restrict__ csr,
                                                const u16* __restrict__ cur,
                                                const u16* __restrict__ hyp,
                                                float* __restrict__ part) {
    __shared__ u16 sc[32 * 68];
    __shared__ u16 sh[32 * 68];
    int bid = blockIdx.x;
    if (bid < LPB) {
        latpart_mfma(bid >> 1, bid & 1, cur, hyp, part, sc, sh);
    } else {
        int sid = bid - LPB;               // LPB%8==0 so sid%8 == bid%8 == XCD
        int xcd = sid & 7;
        int bucket = xcd & 3;
        int chunk = (sid >> 3) * 2 + (xcd >> 2);   // 0..6249
        scatter_body(chunk, bucket, pos, cols, vals, csr);
    }
}

// fused: latreduce (32 blocks, first) || spmm (25000 blocks)
__global__ __launch_bounds__(256) void k_fused_sl(const int* __restrict__ row_start,
                                                  const int2* __restrict__ csr,
                                                  const u16* __restrict__ gate,
                                                  float* __restrict__ out0,
                                                  const float* __restrict__ part,
                                                  float* __restrict__ lat) {
    int bid = blockIdx.x;
    if (bid < 32) latreduce_body(bid, part, lat);
    else          spmm_body(bid - 32, row_start, csr, gate, out0);
}

// layer-1 latpart standalone (MFMA)
__global__ __launch_bounds__(256) void k_latpart1(const u16* __restrict__ cur,
                                                  const u16* __restrict__ hyp,
                                                  float* __restrict__ part) {
    __shared__ u16 sc[32 * 68];
    __shared__ u16 sh[32 * 68];
    int bid = blockIdx.x;                  // grid = LPB
    latpart_mfma(bid >> 1, bid & 1, cur, hyp, part, sc, sh);
}

// hyperLat = leaky(hyp @ lat); outL = hyperLat; cur = bf16(hyperLat + tem);
// if emit: gate = bf16(cur) * (2*sigmoid(z)-1).
__global__ __launch_bounds__(256) void k_hyperlat(const u16* __restrict__ hyp,
                                                  const float* __restrict__ lat,
                                                  const float* __restrict__ tem0,
                                                  float* __restrict__ outL,
                                                  u16* __restrict__ cur,
                                                  const float* __restrict__ z,
                                                  u16* __restrict__ gate,
                                                  int emit) {
    __shared__ float lds[HHY * DD];   // 32 KB
    int t = threadIdx.x;
    for (int i = t; i < HHY * DD / 4; i += 256)
        ((float4*)lds)[i] = ((const float4*)lat)[i];
    __syncthreads();
    int w = t >> 6, l = t & 63;
    int rl = l >> 2, dq = l & 3;
    int r = blockIdx.x * 16 + rl;          // 16 rows per block
    int d0 = w * 16 + dq * 4;
    float a0 = 0.f, a1 = 0.f, a2 = 0.f, a3 = 0.f;
    const u16* hrow = hyp + (size_t)r * HHY;
    for (int h0 = 0; h0 < HHY; h0 += 8) {
        ushort4 p0 = *(const ushort4*)(hrow + h0);
        ushort4 p1 = *(const ushort4*)(hrow + h0 + 4);
        u16 hv[8] = { p0.x, p0.y, p0.z, p0.w, p1.x, p1.y, p1.z, p1.w };
#pragma unroll
        for (int j = 0; j < 8; j++) {
            float hvf = us2f(hv[j]);
            float4 lv = *(const float4*)(lds + (h0 + j) * DD + d0);
            a0 += hvf * lv.x; a1 += hvf * lv.y;
            a2 += hvf * lv.z; a3 += hvf * lv.w;
        }
    }
    size_t off = (size_t)r * DD + d0;
    float h0_ = lrelu(a0), h1_ = lrelu(a1), h2_ = lrelu(a2), h3_ = lrelu(a3);
    float4 tem = *(const float4*)(tem0 + off);
    *(float4*)(outL + off) = make_float4(h0_, h1_, h2_, h3_);
    ushort4 cb;
    cb.x = f2us(h0_ + tem.x); cb.y = f2us(h1_ + tem.y);
    cb.z = f2us(h2_ + tem.z); cb.w = f2us(h3_ + tem.w);
    *(ushort4*)(cur + off) = cb;
    if (emit) {
        float4 zz = *(const float4*)(z + off);
        ushort4 g;
        g.x = f2us(us2f(cb.x) * (2.f / (1.f + __expf(-zz.x)) - 1.f));
        g.y = f2us(us2f(cb.y) * (2.f / (1.f + __expf(-zz.y)) - 1.f));
        g.z = f2us(us2f(cb.z) * (2.f / (1.f + __expf(-zz.z)) - 1.f));
        g.w = f2us(us2f(cb.w) * (2.f / (1.f + __expf(-zz.w)) - 1.f));
        *(ushort4*)(gate + off) = g;
    }
}

// ---------------- launch ----------------

extern "C" void kernel_launch(void* const* d_in, const int* in_sizes, int n_in,
                              void* d_out, int out_size, void* d_ws, size_t ws_size,
                              hipStream_t stream) {
    const int*   rows  = (const int*)d_in[0];    // int32
    const int*   cols  = (const int*)d_in[1];    // int32
    const float* vals  = (const float*)d_in[2];  // fp32
    const float* uEmb  = (const float*)d_in[3];  // fp32
    const float* iEmb  = (const float*)d_in[4];  // fp32
    const float* Hyper = (const float*)d_in[5];  // fp32
    const float* zishi = (const float*)d_in[6];  // fp32
    // d_in[7] = keepRate (==1, static python branch) -> unused

    float* out = (float*)d_out;                  // fp32 output, [3, NN, DD]

    char* ws = (char*)d_ws;
    int2*  csr       = (int2*)(ws + 0);                 // 12,800,000
    int*   row_start = (int*)(ws + 12800000);           //    400,128 (padded)
    int*   counts    = (int*)(ws + 13600128);           //    400,000
    u16*   hyp       = (u16*)(ws + 14000128);           // 25,600,000
    u16*   cur       = (u16*)(ws + 39600128);           // 12,800,000
    float* lat       = (float*)(ws + 52400128);         //     32,768
    int*   bsum      = (int*)(ws + 52432896);           //      1,564 -> end 52,434,460

    // Scratch aliasing:
    //  out slab1 [25.6M, 38.4M): gate0 (bf16, 12.8 MB) — written k_hp_ah, last read
    //      k_fused_sl(l0); then k_hyperlat(l0) overwrites slab1 with hyperLat1.
    //  out slab2 [51.2M, 76.8M):
    //   ranks (int,  6.4 MB) @ [0, 6.4M):    written k_hp_ah, last read k_pos.
    //   pos   (int,  6.4 MB) @ [6.4M,12.8M): written k_pos,  last read k_fused0.
    //   gate1 (bf16, 12.8 MB) @ [0, 12.8M):  written k_hyperlat(l0 epilogue, after
    //                                        ranks/pos dead), last read k_fused_sl(l1).
    //   part  (fp32, 11.53 MB) @ [12.8M, 24.34M): written k_fused0/k_latpart1,
    //                                        last read k_fused_sl of same layer.
    //  Final k_hyperlat(l=1) writes hyperLat2 over slab2 last (gate1+part dead).
    char*  slab2 = (char*)(out + (size_t)2 * NN * DD);
    u16*   gate0 = (u16*)(out + (size_t)1 * NN * DD);
    int*   ranks = (int*)slab2;
    int*   pos   = (int*)(slab2 + 6400000);
    u16*   gate1 = (u16*)slab2;
    float* part  = (float*)(slab2 + 12800000);

    // CSR build + embeds prep + gate0 + allhyper (fused)
    hipMemsetAsync(counts, 0, NN * sizeof(int), stream);
    k_hp_ah<<<2 * SCB, 256, 0, stream>>>(rows, counts, ranks,
                                         (const float4*)uEmb, (const float4*)iEmb,
                                         (ushort4*)cur, Hyper, hyp,
                                         (const float4*)zishi, (ushort4*)gate0);
    k_blocksum<<<NSB, 256, 0, stream>>>(counts, bsum);
    k_scanb<<<1, 512, 0, stream>>>(bsum);
    k_scanfinal<<<NSB, 256, 0, stream>>>(counts, bsum, row_start);
    k_pos<<<SCB, 256, 0, stream>>>(rows, ranks, row_start, pos);

    float* out0 = out;  // tem slab (layer-2 spmm overwrites it, matching reference)

    // ---- layer 0 ----
    k_fused0<<<LPB + 8 * 3125, 256, 0, stream>>>(pos, cols, vals, csr, cur, hyp, part);
    k_fused_sl<<<NN / 4 + 32, 256, 0, stream>>>(row_start, csr, gate0, out0, part, lat);
    k_hyperlat<<<NN / 16, 256, 0, stream>>>(hyp, lat, out0, out + (size_t)1 * NN * DD, cur,
                                            zishi, gate1, 1);   // emits gate1

    // ---- layer 1 ----
    k_latpart1<<<LPB, 256, 0, stream>>>(cur, hyp, part);
    k_fused_sl<<<NN / 4 + 32, 256, 0, stream>>>(row_start, csr, gate1, out0, part, lat);
    k_hyperlat<<<NN / 16, 256, 0, stream>>>(hyp, lat, out0, out + (size_t)2 * NN * DD, cur,
                                            zishi, gate1, 0);
}